// Round 7
// baseline (45.164 us; speedup 1.0000x reference)
//
#include <hip/hip_runtime.h>

// LIFSpike forward scan: x [B,N,T] fp32, Vth [N], tau [N] -> out [B,N,T] fp32
// u_t = tau*(u_{t-1} - Vth*o_{t-1}) + x_t ; o_t = (u_t - Vth > 0) ? 1 : 0
//
// R7 = R6 with the nontemporal store done through a native clang vector type
// (HIP's float4 class is rejected by __builtin_nontemporal_store).
// Structure: single-wave blocks, 16 KB LDS tile, 16 B-vectorized everywhere,
// block-preserving XOR swizzle:
//   word (row,t) at (row<<6) | (t&3) | (((t>>2) ^ (row&15)) << 2)

typedef float v4f __attribute__((ext_vector_type(4)));  // native vector for builtins

constexpr int B = 128;
constexpr int N = 4096;
constexpr int T = 64;
constexpr int ROWS = 64;              // rows per block = 1 wave
constexpr int TILE_WORDS = ROWS * T;  // 4096 words = 16 KB

__global__ __launch_bounds__(64) void lif_spike_kernel(
    const float* __restrict__ x,
    const float* __restrict__ Vth,
    const float* __restrict__ tau,
    float* __restrict__ out)
{
    __shared__ float lds[TILE_WORDS];  // 16 KB

    const int tid = threadIdx.x;       // 0..63
    const long long tile_base = (long long)blockIdx.x * TILE_WORDS;

    // ---- Phase A: global dwordx4 -> LDS b128 (block-swizzled) ----
    const v4f* __restrict__ xp = reinterpret_cast<const v4f*>(x + tile_base);
    #pragma unroll
    for (int k = 0; k < 16; ++k) {
        const v4f v = xp[k * 64 + tid];             // wave: 1024 B contiguous
        const int row  = k * 4 + (tid >> 4);
        const int q    = tid & 15;                  // t-group index
        const int idx  = (row << 6) | ((q ^ (row & 15)) << 2);
        *reinterpret_cast<v4f*>(&lds[idx]) = v;
    }
    __syncthreads();

    // ---- Phase B: scan own row, 4 t-steps per b128 read/write ----
    {
        const long long grow = (long long)blockIdx.x * ROWS + tid;
        const int n = (int)(grow & (N - 1));

        const float vth = fmaxf(Vth[n], 0.0f);             // constrain 'forward'
        const float tc  = fminf(fmaxf(tau[n], 0.0f), 1.0f);

        float u = 0.0f, o = 0.0f;
        const int base = tid << 6;
        const int p    = tid & 15;
        #pragma unroll
        for (int q = 0; q < 16; ++q) {
            const int idx = base | ((q ^ p) << 2);  // block holding t=4q..4q+3
            const v4f xx = *reinterpret_cast<const v4f*>(&lds[idx]);
            v4f r;
            u = tc * (u - vth * o) + xx.x; o = (u > vth) ? 1.0f : 0.0f; r.x = o;
            u = tc * (u - vth * o) + xx.y; o = (u > vth) ? 1.0f : 0.0f; r.y = o;
            u = tc * (u - vth * o) + xx.z; o = (u > vth) ? 1.0f : 0.0f; r.z = o;
            u = tc * (u - vth * o) + xx.w; o = (u > vth) ? 1.0f : 0.0f; r.w = o;
            *reinterpret_cast<v4f*>(&lds[idx]) = r;
        }
    }
    __syncthreads();

    // ---- Phase C: LDS b128 -> global dwordx4, nontemporal ----
    v4f* __restrict__ op = reinterpret_cast<v4f*>(out + tile_base);
    #pragma unroll
    for (int k = 0; k < 16; ++k) {
        const int row = k * 4 + (tid >> 4);
        const int q   = tid & 15;
        const int idx = (row << 6) | ((q ^ (row & 15)) << 2);
        const v4f v = *reinterpret_cast<const v4f*>(&lds[idx]);
        __builtin_nontemporal_store(v, &op[k * 64 + tid]);  // wave: 1024 B contiguous
    }
}

extern "C" void kernel_launch(void* const* d_in, const int* in_sizes, int n_in,
                              void* d_out, int out_size, void* d_ws, size_t ws_size,
                              hipStream_t stream) {
    const float* x   = (const float*)d_in[0];
    const float* Vth = (const float*)d_in[1];
    const float* tau = (const float*)d_in[2];
    float* out       = (float*)d_out;

    const int grid = (B * N) / ROWS;  // 8192 blocks
    lif_spike_kernel<<<grid, 64, 0, stream>>>(x, Vth, tau, out);
}

// Round 8
// 44.076 us; speedup vs baseline: 1.0247x; 1.0247x over previous
//
#include <hip/hip_runtime.h>

// LIFSpike forward scan: x [B,N,T] fp32, Vth [N], tau [N] -> out [B,N,T] fp32
// u_t = tau*(u_{t-1} - Vth*o_{t-1}) + x_t ; o_t = (u_t - Vth > 0) ? 1 : 0
//
// FINAL (= R5, best measured: 43.9 us = 93% of the 6.29 TB/s copy ceiling
// for the mandatory 256 MB logical traffic).
// Structure: one wave per block, 64 rows x 64 t = 16 KB LDS tile.
//   Phase A: coalesced global->LDS (256 B/instr), 5-bit XOR row swizzle
//   Phase B: per-thread in-register scan of its own row in LDS
//            (swizzle => exactly 2 lanes/bank at every t = conflict-free)
//   Phase C: coalesced LDS->global nontemporal stores (full-line writes,
//            WRITE_SIZE = ideal 128 MB)
// Proven non-levers: occupancy (R2 18% == R3 35% in TB/s), 16B vectorization
// (R7 neutral), chunked stores (R3: partial-line RMW +26 MB writes).

constexpr int B = 128;
constexpr int N = 4096;
constexpr int T = 64;
constexpr int ROWS = 64;              // rows (sequences) per block = 1 wave
constexpr int TILE_WORDS = ROWS * T;  // 4096 words = 16 KB

__global__ __launch_bounds__(64) void lif_spike_kernel(
    const float* __restrict__ x,
    const float* __restrict__ Vth,
    const float* __restrict__ tau,
    float* __restrict__ out)
{
    __shared__ float lds[TILE_WORDS];  // 16 KB

    const int tid = threadIdx.x;       // 0..63
    const long long tile_base = (long long)blockIdx.x * TILE_WORDS;

    // ---- Phase A: coalesced global -> LDS (swizzled) ----
    #pragma unroll
    for (int k = 0; k < 64; ++k) {
        const int widx = k * 64 + tid;       // wave: 256 B contiguous / instr
        const int row  = k;
        const int t    = tid;
        lds[(row << 6) | (t ^ (row & 31))] = x[tile_base + widx];
    }
    __syncthreads();

    // ---- Phase B: scan own row in LDS (conflict-free via XOR swizzle) ----
    {
        const long long grow = (long long)blockIdx.x * ROWS + tid;  // global row
        const int n = (int)(grow & (N - 1));

        const float vth = fmaxf(Vth[n], 0.0f);             // constrain 'forward'
        const float tc  = fminf(fmaxf(tau[n], 0.0f), 1.0f);

        float u = 0.0f, o = 0.0f;
        const int base = tid << 6;
        const int c    = tid & 31;
        #pragma unroll
        for (int t = 0; t < 64; ++t) {
            const int idx = base | (t ^ c);
            const float xt = lds[idx];
            u = tc * (u - vth * o) + xt;
            o = (u > vth) ? 1.0f : 0.0f;
            lds[idx] = o;   // in-place: same thread owns the row
        }
    }
    __syncthreads();

    // ---- Phase C: coalesced LDS -> global, nontemporal ----
    #pragma unroll
    for (int k = 0; k < 64; ++k) {
        const int widx = k * 64 + tid;
        const int row  = k;
        const int t    = tid;
        const float v  = lds[(row << 6) | (t ^ (row & 31))];
        __builtin_nontemporal_store(v, &out[tile_base + widx]);
    }
}

extern "C" void kernel_launch(void* const* d_in, const int* in_sizes, int n_in,
                              void* d_out, int out_size, void* d_ws, size_t ws_size,
                              hipStream_t stream) {
    const float* x   = (const float*)d_in[0];
    const float* Vth = (const float*)d_in[1];
    const float* tau = (const float*)d_in[2];
    float* out       = (float*)d_out;

    const int grid = (B * N) / ROWS;  // 8192 blocks
    lif_spike_kernel<<<grid, 64, 0, stream>>>(x, Vth, tau, out);
}